// Round 14
// baseline (82.643 us; speedup 1.0000x reference)
//
#include <hip/hip_runtime.h>

// patches: [N=128, C=4, P=32, P, P] fp32 ; vol/out: [B=2, C=4, 128,128,128] fp32
// centers: [N,3] int32 ; lo = center-16 (lo in [0,96]) ; patch n -> batch b = n/64
// out = 0.5*vol + 0.5*scatter(patches), computed as a GATHER (no atomics).
// R14: SPLIT the per-wave candidate chain across the block's 4 waves.
//  - block footprint = 2 w-columns (65536 blocks); all 4 waves compute the
//    same ~4-candidate ballot; wave q handles candidates j%4==q (wave-uniform
//    branch, no divergence) -> per-wave dependent gather chain ~7 -> ~1.3
//  - partial float4 accumulators reduced through 3KB LDS, one barrier;
//    wave 0 loads vol early and writes out
//  - channel-split mapping (1 thread = 1 channel x 4 d), aligned ka/kb float4
//    gather + wave-uniform shift (k0&3 lane-invariant), VGPR stays ~24

constexpr int C = 4, H = 128, P = 32;
constexpr int NPB  = 64;               // patches per batch
constexpr int PCH4 = P * P * P / 4;    // patch channel stride in float4 (8192)

__global__ __launch_bounds__(256) void patch_gather_kernel(
        const float4* __restrict__ patches4,
        const int*   __restrict__ centers,
        const float4* __restrict__ vol4,
        float4* __restrict__ out4) {
    __shared__ float4 sacc[3][64];     // partial sums of waves 1..3

    int blk = blockIdx.x;              // (((b*4 + c)*128 + h)*64 + wp)
    int wp   = blk & 63;
    int h    = (blk >> 6) & 127;
    int c    = (blk >> 13) & 3;
    int b    = blk >> 15;
    int tid  = threadIdx.x;
    int lane = tid & 63;
    int widx = tid >> 6;

    int wlo = wp << 1;                 // block covers w in {wlo, wlo+1}
    int d4  = lane & 31;
    int w   = wlo + (lane >> 5);
    int d0  = d4 << 2;

    // only wave 0 writes out -> only wave 0 needs vol (issued EARLY)
    int base4 = (((b * C + c) * H + h) * H + w) * 32 + d4;
    float4 v = make_float4(0.f, 0.f, 0.f, 0.f);
    if (widx == 0) v = vol4[base4];

    // ---- wave-autonomous filter: lane l evaluates patch l --------------
    int cb  = (b * NPB + lane) * 3;
    int lo0 = centers[cb + 0] - 16;    // in [0,96]
    int lo1 = centers[cb + 1] - 16;
    int lo2 = centers[cb + 2] - 16;
    bool cand = ((unsigned)(h - lo0) < 32u) &&
                ((unsigned)(wlo - lo1 + 1) < 33u);     // {wlo,wlo+1} intersect
    int packed = ((h - lo0) << 14) | (lo1 << 7) | lo2; // hi | lo1 | lo2
    unsigned long long mask = __ballot(cand);

    float4 acc = make_float4(0.f, 0.f, 0.f, 0.f);
    const float4* pbat = patches4 + ((size_t)b * NPB * C + c) * PCH4;

    int j = 0;
    while (mask) {
        int l = __ffsll((long long)mask) - 1;          // candidate = lane l
        mask &= mask - 1;
        if ((j & 3) == widx) {         // this wave's share (wave-uniform)
            int e = __shfl(packed, l); // broadcast descriptor
            int hi   = (e >> 14) & 31;
            int plo1 = (e >> 7) & 127;
            int plo2 = e & 127;
            int wi = w - plo1;
            int k0 = d0 - plo2;        // patch-k of this thread's first elem
            bool hit = ((unsigned)wi < 32u) && (k0 > -4) && (k0 < 32);

            float4 z = make_float4(0.f, 0.f, 0.f, 0.f);
            float4 A = z, Bv = z;
            if (hit) {
                int q = (k0 + 4) >> 2; // 0..8
                int ka = q - 1, kb = q;
                const float4* pr = pbat + (size_t)l * C * PCH4
                                 + (hi * 32 + wi) * 8;
                if ((unsigned)ka < 8u) A  = pr[ka];
                if ((unsigned)kb < 8u) Bv = pr[kb];
            }
            // k0 & 3 lane-invariant (d0 % 4 == 0)
            int shift = __builtin_amdgcn_readfirstlane(k0 & 3);
            switch (shift) {
            case 0:
                acc.x += A.x; acc.y += A.y; acc.z += A.z; acc.w += A.w; break;
            case 1:
                acc.x += A.y; acc.y += A.z; acc.z += A.w; acc.w += Bv.x; break;
            case 2:
                acc.x += A.z; acc.y += A.w; acc.z += Bv.x; acc.w += Bv.y; break;
            default:
                acc.x += A.w; acc.y += Bv.x; acc.z += Bv.y; acc.w += Bv.z; break;
            }
        }
        ++j;
    }

    // ---- combine the 4 waves' partials ---------------------------------
    if (widx > 0) sacc[widx - 1][lane] = acc;
    __syncthreads();
    if (widx == 0) {
        float4 p0 = sacc[0][lane];
        float4 p1 = sacc[1][lane];
        float4 p2 = sacc[2][lane];
        float4 o;
        o.x = (v.x + acc.x + p0.x + p1.x + p2.x) * 0.5f;
        o.y = (v.y + acc.y + p0.y + p1.y + p2.y) * 0.5f;
        o.z = (v.z + acc.z + p0.z + p1.z + p2.z) * 0.5f;
        o.w = (v.w + acc.w + p0.w + p1.w + p2.w) * 0.5f;
        out4[base4] = o;
    }
}

extern "C" void kernel_launch(void* const* d_in, const int* in_sizes, int n_in,
                              void* d_out, int out_size, void* d_ws, size_t ws_size,
                              hipStream_t stream) {
    const float* patches = (const float*)d_in[0];
    const float* vol     = (const float*)d_in[1];
    const int*   centers = (const int*)d_in[2];
    float* out = (float*)d_out;

    patch_gather_kernel<<<65536, 256, 0, stream>>>(
        (const float4*)patches, centers, (const float4*)vol, (float4*)out);
}

// Round 16
// 82.365 us; speedup vs baseline: 1.0034x; 1.0034x over previous
//
#include <hip/hip_runtime.h>

// patches: [N=128, C=4, P=32, P, P] fp32 ; vol/out: [B=2, C=4, 128,128,128] fp32
// centers: [N,3] int32 ; lo = center-16 (lo in [0,96]) ; patch n -> batch b = n/64
// out = 0.5*vol + 0.5*scatter(patches), computed as a GATHER (no atomics).
// R15: BRANCHLESS 4-unrolled candidate walk.
//  - all gather addresses CLAMPED (always-legal loads), validity folded into
//    per-element multiplier masks -> zero control flow between loads; 4
//    candidates' 8 loads issue back-to-back before the first accumulate
//    (R13 post-mortem: branchy ping-pong re-serialized; this is straight-line)
//  - channel-split mapping (R10/R11): 1 thread = 1 channel x 4 d, 16384 blocks
//  - wave-autonomous ballot filter (R11): no LDS, no __syncthreads
//  - f[] concat identity: A=pr[ka],B=pr[kb] hold floats 4ka..4ka+7 and
//    f[shift+j] = row-float k0+j (shift=k0&3 wave-uniform); clamped ka/kb
//    deliver garbage only at k outside [0,32) which the mask zeroes.

constexpr int C = 4, H = 128, P = 32;
constexpr int NPB  = 64;               // patches per batch
constexpr int PCH4 = P * P * P / 4;    // patch channel stride in float4 (8192)

__global__ __launch_bounds__(256) void patch_gather_kernel(
        const float4* __restrict__ patches4,
        const int*   __restrict__ centers,
        const float4* __restrict__ vol4,
        float4* __restrict__ out4) {
    int blk = blockIdx.x;              // (((b*4 + c)*128 + h)*16 + wgrp)
    int wgrp = blk & 15;
    int h    = (blk >> 4) & 127;
    int c    = (blk >> 11) & 3;
    int b    = blk >> 13;
    int tid  = threadIdx.x;

    int w0 = wgrp << 3;                // block covers w0..w0+7
    int d4 = tid & 31;
    int w  = w0 + (tid >> 5);
    int d0 = d4 << 2;

    // ---- issue vol load EARLY ------------------------------------------
    int base4 = (((b * C + c) * H + h) * H + w) * 32 + d4;
    float4 v = vol4[base4];

    // ---- wave-autonomous filter: lane l evaluates patch l --------------
    int lane = tid & 63;
    int cb   = (b * NPB + lane) * 3;
    int lo0  = centers[cb + 0] - 16;   // in [0,96]
    int lo1  = centers[cb + 1] - 16;
    int lo2  = centers[cb + 2] - 16;
    int wlo  = w0 + ((tid >> 6) << 1); // this wave covers {wlo, wlo+1}
    bool cand = ((unsigned)(h - lo0) < 32u) &&
                ((unsigned)(wlo - lo1 + 1) < 33u);     // window intersect
    int packed = ((h - lo0) << 14) | (lo1 << 7) | lo2; // hi | lo1 | lo2
    unsigned long long mask = __ballot(cand);

    float4 acc = make_float4(0.f, 0.f, 0.f, 0.f);
    const float4* pbat = patches4 + ((size_t)b * NPB * C + c) * PCH4;

    while (mask) {
        // ---- issue phase: 4 candidates, 8 unconditional clamped loads ---
        float4 A[4], Bv[4];
        int   k0v[4];
        float hitf[4];
        int   shv[4];
        #pragma unroll
        for (int s = 0; s < 4; ++s) {
            bool has = (mask != 0ull);
            int l_  = __ffsll((long long)mask) - 1;    // -1 when empty
            mask &= mask - 1ull;                       // 0 stays 0
            int lc  = has ? l_ : 0;
            int e   = __shfl(packed, lc);              // uniform broadcast
            int hi   = (e >> 14) & 31;
            int plo1 = (e >> 7) & 127;
            int plo2 = e & 127;
            int wi = w - plo1;
            int k0 = d0 - plo2;
            bool hit = has && ((unsigned)wi < 32u) && (k0 > -4) && (k0 < 32);
            int wic = min(max(wi, 0), 31);
            int q   = min(max((k0 + 4) >> 2, 0), 8);
            int ka  = max(q - 1, 0);
            int kb  = min(q, 7);
            const float4* pr = pbat + (size_t)lc * C * PCH4
                             + (hi * 32 + wic) * 8;
            A[s]  = pr[ka];                            // always legal
            Bv[s] = pr[kb];
            k0v[s]  = k0;
            hitf[s] = hit ? 1.0f : 0.0f;
            shv[s]  = k0 & 3;      // = (-plo2)&3, lane-invariant (d0%4==0)
        }
        // ---- accumulate phase: masks recomputed, fma with validity ------
        #pragma unroll
        for (int s = 0; s < 4; ++s) {
            int shift = __builtin_amdgcn_readfirstlane(shv[s]);
            int k0 = k0v[s];
            float m0 = ((unsigned)(k0 + 0) < 32u) ? hitf[s] : 0.0f;
            float m1 = ((unsigned)(k0 + 1) < 32u) ? hitf[s] : 0.0f;
            float m2 = ((unsigned)(k0 + 2) < 32u) ? hitf[s] : 0.0f;
            float m3 = ((unsigned)(k0 + 3) < 32u) ? hitf[s] : 0.0f;
            float4 Aa = A[s], Bb = Bv[s];
            switch (shift) {
            case 0:
                acc.x = fmaf(m0, Aa.x, acc.x); acc.y = fmaf(m1, Aa.y, acc.y);
                acc.z = fmaf(m2, Aa.z, acc.z); acc.w = fmaf(m3, Aa.w, acc.w);
                break;
            case 1:
                acc.x = fmaf(m0, Aa.y, acc.x); acc.y = fmaf(m1, Aa.z, acc.y);
                acc.z = fmaf(m2, Aa.w, acc.z); acc.w = fmaf(m3, Bb.x, acc.w);
                break;
            case 2:
                acc.x = fmaf(m0, Aa.z, acc.x); acc.y = fmaf(m1, Aa.w, acc.y);
                acc.z = fmaf(m2, Bb.x, acc.z); acc.w = fmaf(m3, Bb.y, acc.w);
                break;
            default:
                acc.x = fmaf(m0, Aa.w, acc.x); acc.y = fmaf(m1, Bb.x, acc.y);
                acc.z = fmaf(m2, Bb.y, acc.z); acc.w = fmaf(m3, Bb.z, acc.w);
                break;
            }
        }
    }

    // ---- epilogue: out = 0.5*(vol + acc) -------------------------------
    float4 o;
    o.x = (v.x + acc.x) * 0.5f;
    o.y = (v.y + acc.y) * 0.5f;
    o.z = (v.z + acc.z) * 0.5f;
    o.w = (v.w + acc.w) * 0.5f;
    out4[base4] = o;
}

extern "C" void kernel_launch(void* const* d_in, const int* in_sizes, int n_in,
                              void* d_out, int out_size, void* d_ws, size_t ws_size,
                              hipStream_t stream) {
    const float* patches = (const float*)d_in[0];
    const float* vol     = (const float*)d_in[1];
    const int*   centers = (const int*)d_in[2];
    float* out = (float*)d_out;

    patch_gather_kernel<<<16384, 256, 0, stream>>>(
        (const float4*)patches, centers, (const float4*)vol, (float4*)out);
}